// Round 1
// 676.991 us; speedup vs baseline: 1.0034x; 1.0034x over previous
//
#include <hip/hip_runtime.h>
#include <hip/hip_bf16.h>

// ---------------- problem constants ----------------
#define T_TOK 2048
#define DMODEL 1024
#define DMLP 4096
#define NEXP 8

// MFMA fragment types (gfx950 16x16x32 bf16)
typedef __bf16 bf16x8 __attribute__((ext_vector_type(8)));
typedef float f32x4 __attribute__((ext_vector_type(4)));

__device__ __forceinline__ unsigned short f2bf(float f) {
  return __builtin_bit_cast(unsigned short, (__bf16)f);
}

// async global->LDS, 16B per lane. LDS dest must be linear: base + lane*16.
__device__ __forceinline__ void gload16(const unsigned short* g,
                                        unsigned short* l) {
  __builtin_amdgcn_global_load_lds(
      (const __attribute__((address_space(1))) unsigned int*)g,
      (__attribute__((address_space(3))) unsigned int*)l, 16, 0, 0);
}

// ---------------- kernel 1: router (unchanged) ----------------
__global__ __launch_bounds__(64) void router_k(
    const float* __restrict__ x, const float* __restrict__ wg,
    int* __restrict__ topi, float* __restrict__ topw) {
  int t = blockIdx.x;
  int lane = threadIdx.x;
  const float* hx = x + (size_t)t * DMODEL;
  float acc[NEXP];
#pragma unroll
  for (int e = 0; e < NEXP; ++e) acc[e] = 0.f;
  for (int i = lane; i < DMODEL; i += 64) {
    float xi = hx[i];
    const float* w = wg + (size_t)i * NEXP;
#pragma unroll
    for (int e = 0; e < NEXP; ++e) acc[e] += xi * w[e];
  }
#pragma unroll
  for (int off = 32; off > 0; off >>= 1) {
#pragma unroll
    for (int e = 0; e < NEXP; ++e) acc[e] += __shfl_down(acc[e], off);
  }
  if (lane == 0) {
    float m = acc[0];
#pragma unroll
    for (int e = 1; e < NEXP; ++e) m = fmaxf(m, acc[e]);
    float p[NEXP], s = 0.f;
#pragma unroll
    for (int e = 0; e < NEXP; ++e) { p[e] = expf(acc[e] - m); s += p[e]; }
    float inv = 1.f / s;
#pragma unroll
    for (int e = 0; e < NEXP; ++e) p[e] *= inv;
    int i1 = 0;
#pragma unroll
    for (int e = 1; e < NEXP; ++e) if (p[e] > p[i1]) i1 = e;
    int i2 = (i1 == 0) ? 1 : 0;
#pragma unroll
    for (int e = 0; e < NEXP; ++e) if (e != i1 && p[e] > p[i2]) i2 = e;
    float w1 = p[i1], w2 = p[i2];
    float rs = 1.f / (w1 + w2);
    topi[2 * t] = i1;
    topi[2 * t + 1] = i2;
    topw[2 * t] = w1 * rs;
    topw[2 * t + 1] = w2 * rs;
  }
}

// ---------------- kernel 2: compaction (+ inverse map) ----------------
__global__ __launch_bounds__(512) void compact_k(
    const int* __restrict__ topi, const float* __restrict__ topw,
    int* __restrict__ offsets, int* __restrict__ perm,
    float* __restrict__ wrow, int* __restrict__ inv) {
  int tid = threadIdx.x;
  int e = tid >> 6, lane = tid & 63;
  __shared__ int scnt[NEXP];
  __shared__ int soff[NEXP + 1];
  int c = 0;
  for (int j = lane; j < 2 * T_TOK; j += 64) {
    unsigned long long m = __ballot(topi[j] == e);
    c += __popcll(m);
  }
  if (lane == 0) scnt[e] = c;
  __syncthreads();
  if (tid == 0) {
    int s = 0;
    for (int k = 0; k < NEXP; ++k) { soff[k] = s; s += scnt[k]; }
    soff[NEXP] = s;
    for (int k = 0; k <= NEXP; ++k) offsets[k] = soff[k];
  }
  __syncthreads();
  int base = soff[e];
  for (int j = lane; j < 2 * T_TOK; j += 64) {
    bool f = (topi[j] == e);
    unsigned long long m = __ballot(f);
    if (f) {
      int p = base + __popcll(m & ((1ULL << lane) - 1ULL));
      perm[p] = j >> 1;
      wrow[p] = topw[j];
      inv[j] = p;  // pair j -> compacted row (for combine kernel)
    }
    base += __popcll(m);
  }
}

// =====================================================================
// NEW PATH: one-time bf16 convert/transpose pre-pass + m97-style GEMMs
// =====================================================================

// x [T][D] fp32 -> bf16
__global__ __launch_bounds__(256) void xcvt_k(const float* __restrict__ x,
                                              unsigned short* __restrict__ xb) {
  int i = blockIdx.x * 256 + threadIdx.x;
  float4 v = ((const float4*)x)[i];
  ushort4 u;
  u.x = f2bf(v.x); u.y = f2bf(v.y); u.z = f2bf(v.z); u.w = f2bf(v.w);
  ((ushort4*)xb)[i] = u;
}

#define TP 72  // transpose LDS pitch (ushorts): keeps 16B-aligned rows

// We_gate / We_in  [e][k=1024][n=4096] fp32 -> [e][n][k] bf16
__global__ __launch_bounds__(256) void tgi_k(
    const float* __restrict__ weg, const float* __restrict__ wei,
    unsigned short* __restrict__ wgt, unsigned short* __restrict__ wit) {
  int z = blockIdx.z; int e = z >> 1; int mat = z & 1;
  const float* src = (mat ? wei : weg) + (size_t)e * DMODEL * DMLP;
  unsigned short* dst = (mat ? wit : wgt) + (size_t)e * DMLP * DMODEL;
  int k0 = blockIdx.y * 64, c0 = blockIdx.x * 64;
  __shared__ unsigned short tl[64 * TP];
  int tid = threadIdx.x;
#pragma unroll
  for (int i = 0; i < 4; ++i) {
    int task = tid + i * 256;
    int r = task >> 4, c4 = (task & 15) * 4;
    float4 v = *(const float4*)(src + (size_t)(k0 + r) * DMLP + c0 + c4);
    tl[(c4 + 0) * TP + r] = f2bf(v.x);
    tl[(c4 + 1) * TP + r] = f2bf(v.y);
    tl[(c4 + 2) * TP + r] = f2bf(v.z);
    tl[(c4 + 3) * TP + r] = f2bf(v.w);
  }
  __syncthreads();
#pragma unroll
  for (int i = 0; i < 2; ++i) {
    int task = tid + i * 256;
    int rr = task >> 3, cc = (task & 7) * 8;
    uint4 v = *(const uint4*)(&tl[rr * TP + cc]);
    *(uint4*)(dst + (size_t)(c0 + rr) * DMODEL + k0 + cc) = v;
  }
}

// We_out [e][k=4096][n=1024] fp32 -> [e][n][k] bf16
__global__ __launch_bounds__(256) void tout_k(
    const float* __restrict__ weo, unsigned short* __restrict__ wot) {
  int e = blockIdx.z;
  const float* src = weo + (size_t)e * DMLP * DMODEL;
  unsigned short* dst = wot + (size_t)e * DMODEL * DMLP;
  int k0 = blockIdx.y * 64, c0 = blockIdx.x * 64;
  __shared__ unsigned short tl[64 * TP];
  int tid = threadIdx.x;
#pragma unroll
  for (int i = 0; i < 4; ++i) {
    int task = tid + i * 256;
    int r = task >> 4, c4 = (task & 15) * 4;
    float4 v = *(const float4*)(src + (size_t)(k0 + r) * DMODEL + c0 + c4);
    tl[(c4 + 0) * TP + r] = f2bf(v.x);
    tl[(c4 + 1) * TP + r] = f2bf(v.y);
    tl[(c4 + 2) * TP + r] = f2bf(v.z);
    tl[(c4 + 3) * TP + r] = f2bf(v.w);
  }
  __syncthreads();
#pragma unroll
  for (int i = 0; i < 2; ++i) {
    int task = tid + i * 256;
    int rr = task >> 3, cc = (task & 7) * 8;
    uint4 v = *(const uint4*)(&tl[rr * TP + cc]);
    *(uint4*)(dst + (size_t)(c0 + rr) * DMLP + k0 + cc) = v;
  }
}

// fused gate/in GEMM, m97 structure: 128x128 tile, BK=32, 4 waves (2x2),
// all-bf16 operands, global_load_lds staging, linear LDS.
// B tile rows: [0:32)=gate nb+0..31, [32:64)=in nb+0..31,
//              [64:96)=gate nb+32..63, [96:128)=in nb+32..63
// -> wave frags j=0,1 gate pair with j=2,3 in at same lane/col.
__global__ __launch_bounds__(256) void hid2_k(
    const unsigned short* __restrict__ xb, const unsigned short* __restrict__ wgt,
    const unsigned short* __restrict__ wit, const int* __restrict__ offsets,
    const int* __restrict__ perm, const float* __restrict__ wrow,
    unsigned short* __restrict__ hid) {
  int e = blockIdx.z;
  int off = offsets[e], end = offsets[e + 1];
  int cnt = end - off;
  int m0 = blockIdx.y * 128;
  if (m0 >= cnt) return;
  int nb = blockIdx.x * 64;  // mlp col base (64 mlp cols per block)

  __shared__ unsigned short As[128 * 32];
  __shared__ unsigned short Bs[128 * 32];

  int tid = threadIdx.x;
  int lane = tid & 63, wid = tid >> 6;
  int wm = (wid & 1) * 64, wn = (wid >> 1) * 64;
  int lr = lane & 15, q = lane >> 4;

  f32x4 acc[4][4];
  f32x4 z = {0.f, 0.f, 0.f, 0.f};
#pragma unroll
  for (int i = 0; i < 4; ++i)
#pragma unroll
    for (int j = 0; j < 4; ++j) acc[i][j] = z;

  // staging plans: 512 16B-tasks per tile, 2 per thread, LDS dest linear.
  const unsigned short* aptr[2];
  const unsigned short* bptr[2];
#pragma unroll
  for (int it = 0; it < 2; ++it) {
    int task = tid + it * 256;
    int r = task >> 2, ch = task & 3;
    int pl = m0 + r;
    int src = perm[off + ((pl < cnt) ? pl : 0)];
    aptr[it] = xb + (size_t)src * DMODEL + ch * 8;
    int arr = (r >> 5) & 1;
    int col = nb + (r & 31) + ((r >> 6) << 5);
    const unsigned short* w =
        (arr ? wit : wgt) + (size_t)e * DMLP * DMODEL;
    bptr[it] = w + (size_t)col * DMODEL + ch * 8;
  }

  for (int k0 = 0; k0 < DMODEL; k0 += 32) {
#pragma unroll
    for (int it = 0; it < 2; ++it) {
      gload16(aptr[it] + k0, &As[(tid + it * 256) * 8]);
      gload16(bptr[it] + k0, &Bs[(tid + it * 256) * 8]);
    }
    __syncthreads();
    bf16x8 af[4], bfr[4];
#pragma unroll
    for (int i = 0; i < 4; ++i)
      af[i] = *(const bf16x8*)(&As[(wm + i * 16 + lr) * 32 + q * 8]);
#pragma unroll
    for (int j = 0; j < 4; ++j)
      bfr[j] = *(const bf16x8*)(&Bs[(wn + j * 16 + lr) * 32 + q * 8]);
#pragma unroll
    for (int i = 0; i < 4; ++i)
#pragma unroll
      for (int j = 0; j < 4; ++j)
        acc[i][j] = __builtin_amdgcn_mfma_f32_16x16x32_bf16(af[i], bfr[j],
                                                            acc[i][j], 0, 0, 0);
    __syncthreads();
  }

  // epilogue: silu(g)*v * wrow -> bf16 hid
  int colbase = nb + (wn ? 32 : 0);
#pragma unroll
  for (int i = 0; i < 4; ++i) {
#pragma unroll
    for (int jp = 0; jp < 2; ++jp) {
#pragma unroll
      for (int r = 0; r < 4; ++r) {
        int row = wm + i * 16 + q * 4 + r;
        int pl = m0 + row;
        if (pl < cnt) {
          int pos = off + pl;
          float g = acc[i][jp][r], vv = acc[i][jp + 2][r];
          float hv = (g / (1.f + expf(-g))) * vv * wrow[pos];
          hid[(size_t)pos * DMLP + colbase + jp * 16 + lr] = f2bf(hv);
        }
      }
    }
  }
}

// out GEMM, m97 structure, plain f32 stores to pair-major tmp (no atomics)
__global__ __launch_bounds__(256) void out2_k(
    const unsigned short* __restrict__ hid, const unsigned short* __restrict__ wot,
    const int* __restrict__ offsets, float* __restrict__ tmp) {
  int e = blockIdx.z;
  int off = offsets[e], end = offsets[e + 1];
  int cnt = end - off;
  int m0 = blockIdx.y * 128;
  if (m0 >= cnt) return;
  int n0 = blockIdx.x * 128;

  __shared__ unsigned short As[128 * 32];
  __shared__ unsigned short Bs[128 * 32];

  int tid = threadIdx.x;
  int lane = tid & 63, wid = tid >> 6;
  int wm = (wid & 1) * 64, wn = (wid >> 1) * 64;
  int lr = lane & 15, q = lane >> 4;

  f32x4 acc[4][4];
  f32x4 z = {0.f, 0.f, 0.f, 0.f};
#pragma unroll
  for (int i = 0; i < 4; ++i)
#pragma unroll
    for (int j = 0; j < 4; ++j) acc[i][j] = z;

  const unsigned short* aptr[2];
  const unsigned short* bptr[2];
#pragma unroll
  for (int it = 0; it < 2; ++it) {
    int task = tid + it * 256;
    int r = task >> 2, ch = task & 3;
    int pl = m0 + r;
    aptr[it] = hid + (size_t)(off + ((pl < cnt) ? pl : 0)) * DMLP + ch * 8;
    bptr[it] = wot + (size_t)e * DMODEL * DMLP + (size_t)(n0 + r) * DMLP + ch * 8;
  }

  for (int k0 = 0; k0 < DMLP; k0 += 32) {
#pragma unroll
    for (int it = 0; it < 2; ++it) {
      gload16(aptr[it] + k0, &As[(tid + it * 256) * 8]);
      gload16(bptr[it] + k0, &Bs[(tid + it * 256) * 8]);
    }
    __syncthreads();
    bf16x8 af[4], bfr[4];
#pragma unroll
    for (int i = 0; i < 4; ++i)
      af[i] = *(const bf16x8*)(&As[(wm + i * 16 + lr) * 32 + q * 8]);
#pragma unroll
    for (int j = 0; j < 4; ++j)
      bfr[j] = *(const bf16x8*)(&Bs[(wn + j * 16 + lr) * 32 + q * 8]);
#pragma unroll
    for (int i = 0; i < 4; ++i)
#pragma unroll
      for (int j = 0; j < 4; ++j)
        acc[i][j] = __builtin_amdgcn_mfma_f32_16x16x32_bf16(af[i], bfr[j],
                                                            acc[i][j], 0, 0, 0);
    __syncthreads();
  }

#pragma unroll
  for (int i = 0; i < 4; ++i)
#pragma unroll
    for (int j = 0; j < 4; ++j)
#pragma unroll
      for (int r = 0; r < 4; ++r) {
        int row = wm + i * 16 + q * 4 + r;
        int pl = m0 + row;
        if (pl < cnt) {
          tmp[(size_t)(off + pl) * DMODEL + n0 + wn + j * 16 + lr] =
              acc[i][j][r];
        }
      }
}

// combine: out[t] = tmp[inv[2t]] + tmp[inv[2t+1]]  (each token has exactly 2)
__global__ __launch_bounds__(256) void comb_k(const float* __restrict__ tmp,
                                              const int* __restrict__ inv,
                                              float* __restrict__ out) {
  int t = blockIdx.x, c = threadIdx.x;
  int i0 = inv[2 * t], i1 = inv[2 * t + 1];
  const float4* t4 = (const float4*)tmp;
  float4 a = t4[(size_t)i0 * 256 + c];
  float4 b = t4[(size_t)i1 * 256 + c];
  float4 o;
  o.x = a.x + b.x; o.y = a.y + b.y; o.z = a.z + b.z; o.w = a.w + b.w;
  ((float4*)out)[(size_t)t * 256 + c] = o;
}

// =====================================================================
// FALLBACK PATH (verified previous kernels, used when ws_size < 245 MiB)
// =====================================================================
#define BPITCH 40

__global__ __launch_bounds__(256) void hid_k(
    const float* __restrict__ x, const float* __restrict__ weg,
    const float* __restrict__ wei, const int* __restrict__ offsets,
    const int* __restrict__ perm, const float* __restrict__ wrow,
    unsigned short* __restrict__ hid) {
  int e = blockIdx.z;
  int off = offsets[e], end = offsets[e + 1];
  int cnt = end - off;
  int m0 = blockIdx.y * 128;
  if (m0 >= cnt) return;
  int nb = blockIdx.x * 64;
  const float* wg = weg + (size_t)e * DMODEL * DMLP;
  const float* wi = wei + (size_t)e * DMODEL * DMLP;

  __shared__ unsigned short As[128 * BPITCH];
  __shared__ unsigned short Bg[64 * BPITCH];
  __shared__ unsigned short Bi[64 * BPITCH];

  int tid = threadIdx.x;
  int lane = tid & 63, wid = tid >> 6;
  int wm = (wid & 1) * 64, wn = (wid >> 1) * 32;
  int lr = lane & 15, q = lane >> 4;

  f32x4 accg[4][2], acci[4][2];
  f32x4 z = {0.f, 0.f, 0.f, 0.f};
#pragma unroll
  for (int i = 0; i < 4; ++i)
#pragma unroll
    for (int j = 0; j < 2; ++j) { accg[i][j] = z; acci[i][j] = z; }

  const float* aptr[4];
  int adst[4];
#pragma unroll
  for (int it = 0; it < 4; ++it) {
    int task = tid + it * 256;
    int r = task >> 3, kc = (task & 7) * 4;
    int pl = m0 + r;
    int src = perm[off + ((pl < cnt) ? pl : 0)];
    aptr[it] = x + (size_t)src * DMODEL + kc;
    adst[it] = r * BPITCH + kc;
  }
  int tn = (tid & 15) * 4, tk = (tid >> 4) * 2;

  for (int k0 = 0; k0 < DMODEL; k0 += 32) {
#pragma unroll
    for (int it = 0; it < 4; ++it) {
      float4 v = *(const float4*)(aptr[it] + k0);
      ushort4 u;
      u.x = f2bf(v.x); u.y = f2bf(v.y); u.z = f2bf(v.z); u.w = f2bf(v.w);
      *(ushort4*)(&As[adst[it]]) = u;
    }
    {
      const float* pg = wg + (size_t)(k0 + tk) * DMLP + nb + tn;
      float4 g0 = *(const float4*)(pg);
      float4 g1 = *(const float4*)(pg + DMLP);
      const float* pi = wi + (size_t)(k0 + tk) * DMLP + nb + tn;
      float4 i0 = *(const float4*)(pi);
      float4 i1 = *(const float4*)(pi + DMLP);
      const float* c0 = (const float*)&g0;
      const float* c1 = (const float*)&g1;
      const float* d0 = (const float*)&i0;
      const float* d1 = (const float*)&i1;
#pragma unroll
      for (int cix = 0; cix < 4; ++cix) {
        ushort2 vg; vg.x = f2bf(c0[cix]); vg.y = f2bf(c1[cix]);
        *(ushort2*)(&Bg[(tn + cix) * BPITCH + tk]) = vg;
        ushort2 vi; vi.x = f2bf(d0[cix]); vi.y = f2bf(d1[cix]);
        *(ushort2*)(&Bi[(tn + cix) * BPITCH + tk]) = vi;
      }
    }
    __syncthreads();
    bf16x8 af[4], bgf[2], bif[2];
#pragma unroll
    for (int i = 0; i < 4; ++i)
      af[i] = *(const bf16x8*)(&As[(wm + i * 16 + lr) * BPITCH + q * 8]);
#pragma unroll
    for (int j = 0; j < 2; ++j) {
      bgf[j] = *(const bf16x8*)(&Bg[(wn + j * 16 + lr) * BPITCH + q * 8]);
      bif[j] = *(const bf16x8*)(&Bi[(wn + j * 16 + lr) * BPITCH + q * 8]);
    }
#pragma unroll
    for (int i = 0; i < 4; ++i)
#pragma unroll
      for (int j = 0; j < 2; ++j) {
        accg[i][j] = __builtin_amdgcn_mfma_f32_16x16x32_bf16(af[i], bgf[j], accg[i][j], 0, 0, 0);
        acci[i][j] = __builtin_amdgcn_mfma_f32_16x16x32_bf16(af[i], bif[j], acci[i][j], 0, 0, 0);
      }
    __syncthreads();
  }
#pragma unroll
  for (int i = 0; i < 4; ++i)
#pragma unroll
    for (int j = 0; j < 2; ++j)
#pragma unroll
      for (int r = 0; r < 4; ++r) {
        int row = wm + i * 16 + q * 4 + r;
        int pl = m0 + row;
        if (pl < cnt) {
          int pos = off + pl;
          float g = accg[i][j][r], vv = acci[i][j][r];
          float hv = (g / (1.f + expf(-g))) * vv * wrow[pos];
          hid[(size_t)pos * DMLP + nb + wn + j * 16 + lr] = f2bf(hv);
        }
      }
}

__global__ __launch_bounds__(256) void out_k(
    const unsigned short* __restrict__ hid, const float* __restrict__ weo,
    const int* __restrict__ offsets, const int* __restrict__ perm,
    float* __restrict__ out) {
  int e = blockIdx.z;
  int off = offsets[e], end = offsets[e + 1];
  int cnt = end - off;
  int m0 = blockIdx.y * 128;
  if (m0 >= cnt) return;
  int nb = blockIdx.x * 64;
  const float* wo = weo + (size_t)e * DMLP * DMODEL;

  __shared__ unsigned short As[128 * BPITCH];
  __shared__ unsigned short Bs[64 * BPITCH];

  int tid = threadIdx.x;
  int lane = tid & 63, wid = tid >> 6;
  int wm = (wid & 1) * 64, wn = (wid >> 1) * 32;
  int lr = lane & 15, q = lane >> 4;

  f32x4 acc[4][2];
  f32x4 z = {0.f, 0.f, 0.f, 0.f};
#pragma unroll
  for (int i = 0; i < 4; ++i)
#pragma unroll
    for (int j = 0; j < 2; ++j) acc[i][j] = z;

  const unsigned short* aptr[2];
  int adst[2];
#pragma unroll
  for (int it = 0; it < 2; ++it) {
    int task = tid + it * 256;
    int r = task >> 2, kg = (task & 3) * 8;
    int pl = m0 + r;
    int src = off + ((pl < cnt) ? pl : 0);
    aptr[it] = hid + (size_t)src * DMLP + kg;
    adst[it] = r * BPITCH + kg;
  }
  int tn = (tid & 15) * 4, tk = (tid >> 4) * 2;

  for (int k0 = 0; k0 < DMLP; k0 += 32) {
#pragma unroll
    for (int it = 0; it < 2; ++it) {
      uint4 v = *(const uint4*)(aptr[it] + k0);
      *(uint4*)(&As[adst[it]]) = v;
    }
    {
      const float* pb = wo + (size_t)(k0 + tk) * DMODEL + nb + tn;
      float4 b0 = *(const float4*)(pb);
      float4 b1 = *(const float4*)(pb + DMODEL);
      const float* c0 = (const float*)&b0;
      const float* c1 = (const float*)&b1;
#pragma unroll
      for (int cix = 0; cix < 4; ++cix) {
        ushort2 vb; vb.x = f2bf(c0[cix]); vb.y = f2bf(c1[cix]);
        *(ushort2*)(&Bs[(tn + cix) * BPITCH + tk]) = vb;
      }
    }
    __syncthreads();
    bf16x8 af[4], bf[2];
#pragma unroll
    for (int i = 0; i < 4; ++i)
      af[i] = *(const bf16x8*)(&As[(wm + i * 16 + lr) * BPITCH + q * 8]);
#pragma unroll
    for (int j = 0; j < 2; ++j)
      bf[j] = *(const bf16x8*)(&Bs[(wn + j * 16 + lr) * BPITCH + q * 8]);
#pragma unroll
    for (int i = 0; i < 4; ++i)
#pragma unroll
      for (int j = 0; j < 2; ++j)
        acc[i][j] = __builtin_amdgcn_mfma_f32_16x16x32_bf16(af[i], bf[j], acc[i][j], 0, 0, 0);
    __syncthreads();
  }
#pragma unroll
  for (int i = 0; i < 4; ++i)
#pragma unroll
    for (int j = 0; j < 2; ++j)
#pragma unroll
      for (int r = 0; r < 4; ++r) {
        int row = wm + i * 16 + q * 4 + r;
        int pl = m0 + row;
        if (pl < cnt) {
          int tok = perm[off + pl];
          atomicAdd(&out[(size_t)tok * DMODEL + nb + wn + j * 16 + lr],
                    acc[i][j][r]);
        }
      }
}

// ---------------- launcher ----------------
extern "C" void kernel_launch(void* const* d_in, const int* in_sizes, int n_in,
                              void* d_out, int out_size, void* d_ws,
                              size_t ws_size, hipStream_t stream) {
  const float* x = (const float*)d_in[0];
  const float* wgate = (const float*)d_in[1];
  const float* weg = (const float*)d_in[2];
  const float* wei = (const float*)d_in[3];
  const float* weo = (const float*)d_in[4];
  float* out = (float*)d_out;

  char* ws = (char*)d_ws;
  const size_t KB = 1024, MB = 1048576;
  // small buffers (both paths)
  int* topi = (int*)(ws + 0 * KB);        // 16 KB
  float* topw = (float*)(ws + 16 * KB);   // 16 KB
  int* offsets = (int*)(ws + 32 * KB);    // 1 KB
  int* perm = (int*)(ws + 33 * KB);       // 16 KB
  float* wrow = (float*)(ws + 49 * KB);   // 16 KB
  int* inv = (int*)(ws + 65 * KB);        // 16 KB

  router_k<<<dim3(T_TOK), dim3(64), 0, stream>>>(x, wgate, topi, topw);
  compact_k<<<dim3(1), dim3(512), 0, stream>>>(topi, topw, offsets, perm, wrow, inv);

  if (ws_size >= (size_t)245 * MB) {
    // big buffers: xb 4MiB, hid 32MiB, tmp 16MiB, wgt/wit/wot 64MiB each
    unsigned short* xb = (unsigned short*)(ws + 1 * MB);
    unsigned short* hid = (unsigned short*)(ws + 5 * MB);
    float* tmp = (float*)(ws + 37 * MB);
    unsigned short* wgt = (unsigned short*)(ws + 53 * MB);
    unsigned short* wit = (unsigned short*)(ws + 117 * MB);
    unsigned short* wot = (unsigned short*)(ws + 181 * MB);

    xcvt_k<<<dim3(T_TOK * DMODEL / 1024), dim3(256), 0, stream>>>(x, xb);
    tgi_k<<<dim3(DMLP / 64, DMODEL / 64, NEXP * 2), dim3(256), 0, stream>>>(
        weg, wei, wgt, wit);
    tout_k<<<dim3(DMODEL / 64, DMLP / 64, NEXP), dim3(256), 0, stream>>>(weo, wot);
    hid2_k<<<dim3(DMLP / 64, T_TOK / 128, NEXP), dim3(256), 0, stream>>>(
        xb, wgt, wit, offsets, perm, wrow, hid);
    out2_k<<<dim3(DMODEL / 128, T_TOK / 128, NEXP), dim3(256), 0, stream>>>(
        hid, wot, offsets, tmp);
    comb_k<<<dim3(T_TOK), dim3(256), 0, stream>>>(tmp, inv, out);
  } else {
    // fallback: previous verified path (needs ~34 MB of ws)
    unsigned short* hid = (unsigned short*)(ws + 96 * KB);
    hipMemsetAsync(d_out, 0, (size_t)out_size * sizeof(float), stream);
    hid_k<<<dim3(DMLP / 64, T_TOK / 128, NEXP), dim3(256), 0, stream>>>(
        x, weg, wei, offsets, perm, wrow, hid);
    out_k<<<dim3(DMODEL / 64, T_TOK / 128, NEXP), dim3(256), 0, stream>>>(
        hid, weo, offsets, perm, out);
  }
}

// Round 2
// 664.357 us; speedup vs baseline: 1.0224x; 1.0190x over previous
//
#include <hip/hip_runtime.h>
#include <hip/hip_bf16.h>

// ---------------- problem constants ----------------
#define T_TOK 2048
#define DMODEL 1024
#define DMLP 4096
#define NEXP 8

// MFMA fragment types (gfx950 16x16x32 bf16)
typedef __bf16 bf16x8 __attribute__((ext_vector_type(8)));
typedef float f32x4 __attribute__((ext_vector_type(4)));

__device__ __forceinline__ unsigned short f2bf(float f) {
  return __builtin_bit_cast(unsigned short, (__bf16)f);
}

// async global->LDS, 16B per lane. LDS dest must be linear: base + lane*16.
__device__ __forceinline__ void gload16(const unsigned short* g,
                                        unsigned short* l) {
  __builtin_amdgcn_global_load_lds(
      (const __attribute__((address_space(1))) unsigned int*)g,
      (__attribute__((address_space(3))) unsigned int*)l, 16, 0, 0);
}

// ---------------- kernel 1: router (+ fused x->bf16 convert) ----------------
__global__ __launch_bounds__(64) void router_k(
    const float* __restrict__ x, const float* __restrict__ wg,
    int* __restrict__ topi, float* __restrict__ topw,
    unsigned short* __restrict__ xb) {
  int t = blockIdx.x;
  int lane = threadIdx.x;
  const float* hx = x + (size_t)t * DMODEL;
  float acc[NEXP];
#pragma unroll
  for (int e = 0; e < NEXP; ++e) acc[e] = 0.f;
  for (int i = lane; i < DMODEL; i += 64) {
    float xi = hx[i];
    if (xb) xb[(size_t)t * DMODEL + i] = f2bf(xi);
    const float* w = wg + (size_t)i * NEXP;
#pragma unroll
    for (int e = 0; e < NEXP; ++e) acc[e] += xi * w[e];
  }
#pragma unroll
  for (int off = 32; off > 0; off >>= 1) {
#pragma unroll
    for (int e = 0; e < NEXP; ++e) acc[e] += __shfl_down(acc[e], off);
  }
  if (lane == 0) {
    float m = acc[0];
#pragma unroll
    for (int e = 1; e < NEXP; ++e) m = fmaxf(m, acc[e]);
    float p[NEXP], s = 0.f;
#pragma unroll
    for (int e = 0; e < NEXP; ++e) { p[e] = expf(acc[e] - m); s += p[e]; }
    float inv = 1.f / s;
#pragma unroll
    for (int e = 0; e < NEXP; ++e) p[e] *= inv;
    int i1 = 0;
#pragma unroll
    for (int e = 1; e < NEXP; ++e) if (p[e] > p[i1]) i1 = e;
    int i2 = (i1 == 0) ? 1 : 0;
#pragma unroll
    for (int e = 0; e < NEXP; ++e) if (e != i1 && p[e] > p[i2]) i2 = e;
    float w1 = p[i1], w2 = p[i2];
    float rs = 1.f / (w1 + w2);
    topi[2 * t] = i1;
    topi[2 * t + 1] = i2;
    topw[2 * t] = w1 * rs;
    topw[2 * t + 1] = w2 * rs;
  }
}

// ---------------- kernel 2: compaction (LDS-staged ballots) ----------------
__global__ __launch_bounds__(512) void compact_k(
    const int* __restrict__ topi, const float* __restrict__ topw,
    int* __restrict__ offsets, int* __restrict__ perm,
    float* __restrict__ wrow, int* __restrict__ inv) {
  int tid = threadIdx.x;
  int e = tid >> 6, lane = tid & 63;
  __shared__ unsigned char st[2 * T_TOK];
  __shared__ int scnt[NEXP];
  __shared__ int soff[NEXP + 1];
  // stage expert ids to LDS (coalesced int4 reads)
  for (int i = tid; i < (2 * T_TOK) / 4; i += 512) {
    int4 v = ((const int4*)topi)[i];
    uchar4 u;
    u.x = (unsigned char)v.x; u.y = (unsigned char)v.y;
    u.z = (unsigned char)v.z; u.w = (unsigned char)v.w;
    ((uchar4*)st)[i] = u;
  }
  __syncthreads();
  int c = 0;
  for (int j = lane; j < 2 * T_TOK; j += 64) {
    unsigned long long m = __ballot(st[j] == e);
    c += __popcll(m);
  }
  if (lane == 0) scnt[e] = c;
  __syncthreads();
  if (tid == 0) {
    int s = 0;
    for (int k = 0; k < NEXP; ++k) { soff[k] = s; s += scnt[k]; }
    soff[NEXP] = s;
    for (int k = 0; k <= NEXP; ++k) offsets[k] = soff[k];
  }
  __syncthreads();
  int base = soff[e];
  for (int j = lane; j < 2 * T_TOK; j += 64) {
    bool f = (st[j] == e);
    unsigned long long m = __ballot(f);
    if (f) {
      int p = base + __popcll(m & ((1ULL << lane) - 1ULL));
      perm[p] = j >> 1;
      wrow[p] = topw[j];
      inv[j] = p;  // pair j -> compacted row (for combine kernel)
    }
    base += __popcll(m);
  }
}

// ---------------- weight convert+transpose, conflict-free ----------------
// src [e][SK][SN] fp32 -> dst [e][SN][SK] bf16. 64x64 tiles, 256 threads.
// Phase 1: each thread reads a 4x4 fp32 block (4x float4, wave-coalesced),
// register-transposes, writes 4x ds_write_b64 into c-major LDS with XOR
// swizzle r ^= 4*((c>>2)&14) -> uniform bank coverage both phases.
// Phase 2: ds_read_b128 (8 k-elems, order-preserving under swizzle) ->
// 16B coalesced global stores.
template <int SK, int SN>
__global__ __launch_bounds__(256) void tpose_k(
    const float* __restrict__ src0, unsigned short* __restrict__ dst0) {
  int e = blockIdx.z;
  const float* src = src0 + (size_t)e * SK * SN;
  unsigned short* dst = dst0 + (size_t)e * SK * SN;
  int k0 = blockIdx.y * 64, c0 = blockIdx.x * 64;
  __shared__ unsigned short tl[64 * 64];
  int tid = threadIdx.x;
  int j = tid & 15, g = tid >> 4;  // col-group, row-group
  int c4 = j * 4, r0 = g * 4;
  const float* sp = src + (size_t)(k0 + r0) * SN + c0 + c4;
  float4 v0 = *(const float4*)(sp);
  float4 v1 = *(const float4*)(sp + SN);
  float4 v2 = *(const float4*)(sp + 2 * SN);
  float4 v3 = *(const float4*)(sp + 3 * SN);
  const float* p0 = (const float*)&v0;
  const float* p1 = (const float*)&v1;
  const float* p2 = (const float*)&v2;
  const float* p3 = (const float*)&v3;
#pragma unroll
  for (int i = 0; i < 4; ++i) {
    int c = c4 + i;
    ushort4 u;
    u.x = f2bf(p0[i]); u.y = f2bf(p1[i]);
    u.z = f2bf(p2[i]); u.w = f2bf(p3[i]);
    int sw = ((c >> 2) & 14) << 2;  // multiple of 8: keeps 8-blocks intact
    *(ushort4*)(&tl[c * 64 + (r0 ^ sw)]) = u;
  }
  __syncthreads();
#pragma unroll
  for (int i = 0; i < 2; ++i) {
    int task = tid + i * 256;
    int rr = task >> 3, cc = task & 7;  // dst row (=src col), k-block
    int sw = ((rr >> 2) & 14) << 2;
    uint4 w = *(const uint4*)(&tl[rr * 64 + ((cc * 8) ^ sw)]);
    *(uint4*)(dst + (size_t)(c0 + rr) * SK + k0 + cc * 8) = w;
  }
}

// ---------------- fused gate/in GEMM (m97 structure, unchanged) ----------------
// B tile rows: [0:32)=gate nb+0..31, [32:64)=in nb+0..31,
//              [64:96)=gate nb+32..63, [96:128)=in nb+32..63
__global__ __launch_bounds__(256) void hid2_k(
    const unsigned short* __restrict__ xb, const unsigned short* __restrict__ wgt,
    const unsigned short* __restrict__ wit, const int* __restrict__ offsets,
    const int* __restrict__ perm, const float* __restrict__ wrow,
    unsigned short* __restrict__ hid) {
  int e = blockIdx.z;
  int off = offsets[e], end = offsets[e + 1];
  int cnt = end - off;
  int m0 = blockIdx.y * 128;
  if (m0 >= cnt) return;
  int nb = blockIdx.x * 64;  // mlp col base (64 mlp cols per block)

  __shared__ unsigned short As[128 * 32];
  __shared__ unsigned short Bs[128 * 32];

  int tid = threadIdx.x;
  int lane = tid & 63, wid = tid >> 6;
  int wm = (wid & 1) * 64, wn = (wid >> 1) * 64;
  int lr = lane & 15, q = lane >> 4;

  f32x4 acc[4][4];
  f32x4 z = {0.f, 0.f, 0.f, 0.f};
#pragma unroll
  for (int i = 0; i < 4; ++i)
#pragma unroll
    for (int j = 0; j < 4; ++j) acc[i][j] = z;

  const unsigned short* aptr[2];
  const unsigned short* bptr[2];
#pragma unroll
  for (int it = 0; it < 2; ++it) {
    int task = tid + it * 256;
    int r = task >> 2, ch = task & 3;
    int pl = m0 + r;
    int src = perm[off + ((pl < cnt) ? pl : 0)];
    aptr[it] = xb + (size_t)src * DMODEL + ch * 8;
    int arr = (r >> 5) & 1;
    int col = nb + (r & 31) + ((r >> 6) << 5);
    const unsigned short* w =
        (arr ? wit : wgt) + (size_t)e * DMLP * DMODEL;
    bptr[it] = w + (size_t)col * DMODEL + ch * 8;
  }

  for (int k0 = 0; k0 < DMODEL; k0 += 32) {
#pragma unroll
    for (int it = 0; it < 2; ++it) {
      gload16(aptr[it] + k0, &As[(tid + it * 256) * 8]);
      gload16(bptr[it] + k0, &Bs[(tid + it * 256) * 8]);
    }
    __syncthreads();
    bf16x8 af[4], bfr[4];
#pragma unroll
    for (int i = 0; i < 4; ++i)
      af[i] = *(const bf16x8*)(&As[(wm + i * 16 + lr) * 32 + q * 8]);
#pragma unroll
    for (int j = 0; j < 4; ++j)
      bfr[j] = *(const bf16x8*)(&Bs[(wn + j * 16 + lr) * 32 + q * 8]);
#pragma unroll
    for (int i = 0; i < 4; ++i)
#pragma unroll
      for (int j = 0; j < 4; ++j)
        acc[i][j] = __builtin_amdgcn_mfma_f32_16x16x32_bf16(af[i], bfr[j],
                                                            acc[i][j], 0, 0, 0);
    __syncthreads();
  }

  int colbase = nb + (wn ? 32 : 0);
#pragma unroll
  for (int i = 0; i < 4; ++i) {
#pragma unroll
    for (int jp = 0; jp < 2; ++jp) {
#pragma unroll
      for (int r = 0; r < 4; ++r) {
        int row = wm + i * 16 + q * 4 + r;
        int pl = m0 + row;
        if (pl < cnt) {
          int pos = off + pl;
          float g = acc[i][jp][r], vv = acc[i][jp + 2][r];
          float hv = (g / (1.f + expf(-g))) * vv * wrow[pos];
          hid[(size_t)pos * DMLP + colbase + jp * 16 + lr] = f2bf(hv);
        }
      }
    }
  }
}

// ---------------- out GEMM (m97 structure, plain stores) ----------------
__global__ __launch_bounds__(256) void out2_k(
    const unsigned short* __restrict__ hid, const unsigned short* __restrict__ wot,
    const int* __restrict__ offsets, float* __restrict__ tmp) {
  int e = blockIdx.z;
  int off = offsets[e], end = offsets[e + 1];
  int cnt = end - off;
  int m0 = blockIdx.y * 128;
  if (m0 >= cnt) return;
  int n0 = blockIdx.x * 128;

  __shared__ unsigned short As[128 * 32];
  __shared__ unsigned short Bs[128 * 32];

  int tid = threadIdx.x;
  int lane = tid & 63, wid = tid >> 6;
  int wm = (wid & 1) * 64, wn = (wid >> 1) * 64;
  int lr = lane & 15, q = lane >> 4;

  f32x4 acc[4][4];
  f32x4 z = {0.f, 0.f, 0.f, 0.f};
#pragma unroll
  for (int i = 0; i < 4; ++i)
#pragma unroll
    for (int j = 0; j < 4; ++j) acc[i][j] = z;

  const unsigned short* aptr[2];
  const unsigned short* bptr[2];
#pragma unroll
  for (int it = 0; it < 2; ++it) {
    int task = tid + it * 256;
    int r = task >> 2, ch = task & 3;
    int pl = m0 + r;
    aptr[it] = hid + (size_t)(off + ((pl < cnt) ? pl : 0)) * DMLP + ch * 8;
    bptr[it] = wot + (size_t)e * DMODEL * DMLP + (size_t)(n0 + r) * DMLP + ch * 8;
  }

  for (int k0 = 0; k0 < DMLP; k0 += 32) {
#pragma unroll
    for (int it = 0; it < 2; ++it) {
      gload16(aptr[it] + k0, &As[(tid + it * 256) * 8]);
      gload16(bptr[it] + k0, &Bs[(tid + it * 256) * 8]);
    }
    __syncthreads();
    bf16x8 af[4], bfr[4];
#pragma unroll
    for (int i = 0; i < 4; ++i)
      af[i] = *(const bf16x8*)(&As[(wm + i * 16 + lr) * 32 + q * 8]);
#pragma unroll
    for (int j = 0; j < 4; ++j)
      bfr[j] = *(const bf16x8*)(&Bs[(wn + j * 16 + lr) * 32 + q * 8]);
#pragma unroll
    for (int i = 0; i < 4; ++i)
#pragma unroll
      for (int j = 0; j < 4; ++j)
        acc[i][j] = __builtin_amdgcn_mfma_f32_16x16x32_bf16(af[i], bfr[j],
                                                            acc[i][j], 0, 0, 0);
    __syncthreads();
  }

#pragma unroll
  for (int i = 0; i < 4; ++i)
#pragma unroll
    for (int j = 0; j < 4; ++j)
#pragma unroll
      for (int r = 0; r < 4; ++r) {
        int row = wm + i * 16 + q * 4 + r;
        int pl = m0 + row;
        if (pl < cnt) {
          tmp[(size_t)(off + pl) * DMODEL + n0 + wn + j * 16 + lr] =
              acc[i][j][r];
        }
      }
}

// combine: out[t] = tmp[inv[2t]] + tmp[inv[2t+1]]
__global__ __launch_bounds__(256) void comb_k(const float* __restrict__ tmp,
                                              const int* __restrict__ inv,
                                              float* __restrict__ out) {
  int t = blockIdx.x, c = threadIdx.x;
  int i0 = inv[2 * t], i1 = inv[2 * t + 1];
  const float4* t4 = (const float4*)tmp;
  float4 a = t4[(size_t)i0 * 256 + c];
  float4 b = t4[(size_t)i1 * 256 + c];
  float4 o;
  o.x = a.x + b.x; o.y = a.y + b.y; o.z = a.z + b.z; o.w = a.w + b.w;
  ((float4*)out)[(size_t)t * 256 + c] = o;
}

// =====================================================================
// FALLBACK PATH (verified, used when ws_size < 245 MiB)
// =====================================================================
#define BPITCH 40

__global__ __launch_bounds__(256) void hid_k(
    const float* __restrict__ x, const float* __restrict__ weg,
    const float* __restrict__ wei, const int* __restrict__ offsets,
    const int* __restrict__ perm, const float* __restrict__ wrow,
    unsigned short* __restrict__ hid) {
  int e = blockIdx.z;
  int off = offsets[e], end = offsets[e + 1];
  int cnt = end - off;
  int m0 = blockIdx.y * 128;
  if (m0 >= cnt) return;
  int nb = blockIdx.x * 64;
  const float* wg = weg + (size_t)e * DMODEL * DMLP;
  const float* wi = wei + (size_t)e * DMODEL * DMLP;

  __shared__ unsigned short As[128 * BPITCH];
  __shared__ unsigned short Bg[64 * BPITCH];
  __shared__ unsigned short Bi[64 * BPITCH];

  int tid = threadIdx.x;
  int lane = tid & 63, wid = tid >> 6;
  int wm = (wid & 1) * 64, wn = (wid >> 1) * 32;
  int lr = lane & 15, q = lane >> 4;

  f32x4 accg[4][2], acci[4][2];
  f32x4 z = {0.f, 0.f, 0.f, 0.f};
#pragma unroll
  for (int i = 0; i < 4; ++i)
#pragma unroll
    for (int j = 0; j < 2; ++j) { accg[i][j] = z; acci[i][j] = z; }

  const float* aptr[4];
  int adst[4];
#pragma unroll
  for (int it = 0; it < 4; ++it) {
    int task = tid + it * 256;
    int r = task >> 3, kc = (task & 7) * 4;
    int pl = m0 + r;
    int src = perm[off + ((pl < cnt) ? pl : 0)];
    aptr[it] = x + (size_t)src * DMODEL + kc;
    adst[it] = r * BPITCH + kc;
  }
  int tn = (tid & 15) * 4, tk = (tid >> 4) * 2;

  for (int k0 = 0; k0 < DMODEL; k0 += 32) {
#pragma unroll
    for (int it = 0; it < 4; ++it) {
      float4 v = *(const float4*)(aptr[it] + k0);
      ushort4 u;
      u.x = f2bf(v.x); u.y = f2bf(v.y); u.z = f2bf(v.z); u.w = f2bf(v.w);
      *(ushort4*)(&As[adst[it]]) = u;
    }
    {
      const float* pg = wg + (size_t)(k0 + tk) * DMLP + nb + tn;
      float4 g0 = *(const float4*)(pg);
      float4 g1 = *(const float4*)(pg + DMLP);
      const float* pi = wi + (size_t)(k0 + tk) * DMLP + nb + tn;
      float4 i0 = *(const float4*)(pi);
      float4 i1 = *(const float4*)(pi + DMLP);
      const float* c0 = (const float*)&g0;
      const float* c1 = (const float*)&g1;
      const float* d0 = (const float*)&i0;
      const float* d1 = (const float*)&i1;
#pragma unroll
      for (int cix = 0; cix < 4; ++cix) {
        ushort2 vg; vg.x = f2bf(c0[cix]); vg.y = f2bf(c1[cix]);
        *(ushort2*)(&Bg[(tn + cix) * BPITCH + tk]) = vg;
        ushort2 vi; vi.x = f2bf(d0[cix]); vi.y = f2bf(d1[cix]);
        *(ushort2*)(&Bi[(tn + cix) * BPITCH + tk]) = vi;
      }
    }
    __syncthreads();
    bf16x8 af[4], bgf[2], bif[2];
#pragma unroll
    for (int i = 0; i < 4; ++i)
      af[i] = *(const bf16x8*)(&As[(wm + i * 16 + lr) * BPITCH + q * 8]);
#pragma unroll
    for (int j = 0; j < 2; ++j) {
      bgf[j] = *(const bf16x8*)(&Bg[(wn + j * 16 + lr) * BPITCH + q * 8]);
      bif[j] = *(const bf16x8*)(&Bi[(wn + j * 16 + lr) * BPITCH + q * 8]);
    }
#pragma unroll
    for (int i = 0; i < 4; ++i)
#pragma unroll
      for (int j = 0; j < 2; ++j) {
        accg[i][j] = __builtin_amdgcn_mfma_f32_16x16x32_bf16(af[i], bgf[j], accg[i][j], 0, 0, 0);
        acci[i][j] = __builtin_amdgcn_mfma_f32_16x16x32_bf16(af[i], bif[j], acci[i][j], 0, 0, 0);
      }
    __syncthreads();
  }
#pragma unroll
  for (int i = 0; i < 4; ++i)
#pragma unroll
    for (int j = 0; j < 2; ++j)
#pragma unroll
      for (int r = 0; r < 4; ++r) {
        int row = wm + i * 16 + q * 4 + r;
        int pl = m0 + row;
        if (pl < cnt) {
          int pos = off + pl;
          float g = accg[i][j][r], vv = acci[i][j][r];
          float hv = (g / (1.f + expf(-g))) * vv * wrow[pos];
          hid[(size_t)pos * DMLP + nb + wn + j * 16 + lr] = f2bf(hv);
        }
      }
}

__global__ __launch_bounds__(256) void out_k(
    const unsigned short* __restrict__ hid, const float* __restrict__ weo,
    const int* __restrict__ offsets, const int* __restrict__ perm,
    float* __restrict__ out) {
  int e = blockIdx.z;
  int off = offsets[e], end = offsets[e + 1];
  int cnt = end - off;
  int m0 = blockIdx.y * 128;
  if (m0 >= cnt) return;
  int nb = blockIdx.x * 64;
  const float* wo = weo + (size_t)e * DMLP * DMODEL;

  __shared__ unsigned short As[128 * BPITCH];
  __shared__ unsigned short Bs[64 * BPITCH];

  int tid = threadIdx.x;
  int lane = tid & 63, wid = tid >> 6;
  int wm = (wid & 1) * 64, wn = (wid >> 1) * 32;
  int lr = lane & 15, q = lane >> 4;

  f32x4 acc[4][2];
  f32x4 z = {0.f, 0.f, 0.f, 0.f};
#pragma unroll
  for (int i = 0; i < 4; ++i)
#pragma unroll
    for (int j = 0; j < 2; ++j) acc[i][j] = z;

  const unsigned short* aptr[2];
  int adst[2];
#pragma unroll
  for (int it = 0; it < 2; ++it) {
    int task = tid + it * 256;
    int r = task >> 2, kg = (task & 3) * 8;
    int pl = m0 + r;
    int src = off + ((pl < cnt) ? pl : 0);
    aptr[it] = hid + (size_t)src * DMLP + kg;
    adst[it] = r * BPITCH + kg;
  }
  int tn = (tid & 15) * 4, tk = (tid >> 4) * 2;

  for (int k0 = 0; k0 < DMLP; k0 += 32) {
#pragma unroll
    for (int it = 0; it < 2; ++it) {
      uint4 v = *(const uint4*)(aptr[it] + k0);
      *(uint4*)(&As[adst[it]]) = v;
    }
    {
      const float* pb = wo + (size_t)(k0 + tk) * DMODEL + nb + tn;
      float4 b0 = *(const float4*)(pb);
      float4 b1 = *(const float4*)(pb + DMODEL);
      const float* c0 = (const float*)&b0;
      const float* c1 = (const float*)&b1;
#pragma unroll
      for (int cix = 0; cix < 4; ++cix) {
        ushort2 vb; vb.x = f2bf(c0[cix]); vb.y = f2bf(c1[cix]);
        *(ushort2*)(&Bs[(tn + cix) * BPITCH + tk]) = vb;
      }
    }
    __syncthreads();
    bf16x8 af[4], bf[2];
#pragma unroll
    for (int i = 0; i < 4; ++i)
      af[i] = *(const bf16x8*)(&As[(wm + i * 16 + lr) * BPITCH + q * 8]);
#pragma unroll
    for (int j = 0; j < 2; ++j)
      bf[j] = *(const bf16x8*)(&Bs[(wn + j * 16 + lr) * BPITCH + q * 8]);
#pragma unroll
    for (int i = 0; i < 4; ++i)
#pragma unroll
      for (int j = 0; j < 2; ++j)
        acc[i][j] = __builtin_amdgcn_mfma_f32_16x16x32_bf16(af[i], bf[j], acc[i][j], 0, 0, 0);
    __syncthreads();
  }
#pragma unroll
  for (int i = 0; i < 4; ++i)
#pragma unroll
    for (int j = 0; j < 2; ++j)
#pragma unroll
      for (int r = 0; r < 4; ++r) {
        int row = wm + i * 16 + q * 4 + r;
        int pl = m0 + row;
        if (pl < cnt) {
          int tok = perm[off + pl];
          atomicAdd(&out[(size_t)tok * DMODEL + nb + wn + j * 16 + lr],
                    acc[i][j][r]);
        }
      }
}

// ---------------- launcher ----------------
extern "C" void kernel_launch(void* const* d_in, const int* in_sizes, int n_in,
                              void* d_out, int out_size, void* d_ws,
                              size_t ws_size, hipStream_t stream) {
  const float* x = (const float*)d_in[0];
  const float* wgate = (const float*)d_in[1];
  const float* weg = (const float*)d_in[2];
  const float* wei = (const float*)d_in[3];
  const float* weo = (const float*)d_in[4];
  float* out = (float*)d_out;

  char* ws = (char*)d_ws;
  const size_t KB = 1024, MB = 1048576;
  int* topi = (int*)(ws + 0 * KB);        // 16 KB
  float* topw = (float*)(ws + 16 * KB);   // 16 KB
  int* offsets = (int*)(ws + 32 * KB);    // 1 KB
  int* perm = (int*)(ws + 33 * KB);       // 16 KB
  float* wrow = (float*)(ws + 49 * KB);   // 16 KB
  int* inv = (int*)(ws + 65 * KB);        // 16 KB

  bool big = ws_size >= (size_t)245 * MB;
  unsigned short* xb = big ? (unsigned short*)(ws + 1 * MB) : nullptr;

  router_k<<<dim3(T_TOK), dim3(64), 0, stream>>>(x, wgate, topi, topw, xb);
  compact_k<<<dim3(1), dim3(512), 0, stream>>>(topi, topw, offsets, perm, wrow, inv);

  if (big) {
    // xb 4MiB@1MB, hid 32MiB@5MB, tmp 16MiB@37MB, wgt/wit/wot 64MiB @53/117/181MB
    unsigned short* hid = (unsigned short*)(ws + 5 * MB);
    float* tmp = (float*)(ws + 37 * MB);
    unsigned short* wgt = (unsigned short*)(ws + 53 * MB);
    unsigned short* wit = (unsigned short*)(ws + 117 * MB);
    unsigned short* wot = (unsigned short*)(ws + 181 * MB);

    tpose_k<DMODEL, DMLP><<<dim3(DMLP / 64, DMODEL / 64, NEXP), dim3(256), 0,
                            stream>>>(weg, wgt);
    tpose_k<DMODEL, DMLP><<<dim3(DMLP / 64, DMODEL / 64, NEXP), dim3(256), 0,
                            stream>>>(wei, wit);
    tpose_k<DMLP, DMODEL><<<dim3(DMODEL / 64, DMLP / 64, NEXP), dim3(256), 0,
                            stream>>>(weo, wot);
    hid2_k<<<dim3(DMLP / 64, T_TOK / 128, NEXP), dim3(256), 0, stream>>>(
        xb, wgt, wit, offsets, perm, wrow, hid);
    out2_k<<<dim3(DMODEL / 128, T_TOK / 128, NEXP), dim3(256), 0, stream>>>(
        hid, wot, offsets, tmp);
    comb_k<<<dim3(T_TOK), dim3(256), 0, stream>>>(tmp, inv, out);
  } else {
    unsigned short* hid = (unsigned short*)(ws + 96 * KB);
    hipMemsetAsync(d_out, 0, (size_t)out_size * sizeof(float), stream);
    hid_k<<<dim3(DMLP / 64, T_TOK / 128, NEXP), dim3(256), 0, stream>>>(
        x, weg, wei, offsets, perm, wrow, hid);
    out_k<<<dim3(DMODEL / 64, T_TOK / 128, NEXP), dim3(256), 0, stream>>>(
        hid, weo, offsets, perm, out);
  }
}

// Round 3
// 661.390 us; speedup vs baseline: 1.0270x; 1.0045x over previous
//
#include <hip/hip_runtime.h>
#include <hip/hip_bf16.h>

// ---------------- problem constants ----------------
#define T_TOK 2048
#define DMODEL 1024
#define DMLP 4096
#define NEXP 8

// MFMA fragment types (gfx950 16x16x32 bf16)
typedef __bf16 bf16x8 __attribute__((ext_vector_type(8)));
typedef float f32x4 __attribute__((ext_vector_type(4)));
typedef unsigned short u16x8 __attribute__((ext_vector_type(8)));

__device__ __forceinline__ unsigned short f2bf(float f) {
  return __builtin_bit_cast(unsigned short, (__bf16)f);
}

// async global->LDS, 16B per lane. LDS dest must be linear: base + lane*16.
__device__ __forceinline__ void gload16(const unsigned short* g,
                                        unsigned short* l) {
  __builtin_amdgcn_global_load_lds(
      (const __attribute__((address_space(1))) unsigned int*)g,
      (__attribute__((address_space(3))) unsigned int*)l, 16, 0, 0);
}

// ---------------- kernel 1: router (+ fused x->bf16 convert) ----------------
__global__ __launch_bounds__(64) void router_k(
    const float* __restrict__ x, const float* __restrict__ wg,
    int* __restrict__ topi, float* __restrict__ topw,
    unsigned short* __restrict__ xb) {
  int t = blockIdx.x;
  int lane = threadIdx.x;
  const float* hx = x + (size_t)t * DMODEL;
  float acc[NEXP];
#pragma unroll
  for (int e = 0; e < NEXP; ++e) acc[e] = 0.f;
  for (int i = lane; i < DMODEL; i += 64) {
    float xi = hx[i];
    if (xb) xb[(size_t)t * DMODEL + i] = f2bf(xi);
    const float* w = wg + (size_t)i * NEXP;
#pragma unroll
    for (int e = 0; e < NEXP; ++e) acc[e] += xi * w[e];
  }
#pragma unroll
  for (int off = 32; off > 0; off >>= 1) {
#pragma unroll
    for (int e = 0; e < NEXP; ++e) acc[e] += __shfl_down(acc[e], off);
  }
  if (lane == 0) {
    float m = acc[0];
#pragma unroll
    for (int e = 1; e < NEXP; ++e) m = fmaxf(m, acc[e]);
    float p[NEXP], s = 0.f;
#pragma unroll
    for (int e = 0; e < NEXP; ++e) { p[e] = expf(acc[e] - m); s += p[e]; }
    float inv = 1.f / s;
#pragma unroll
    for (int e = 0; e < NEXP; ++e) p[e] *= inv;
    int i1 = 0;
#pragma unroll
    for (int e = 1; e < NEXP; ++e) if (p[e] > p[i1]) i1 = e;
    int i2 = (i1 == 0) ? 1 : 0;
#pragma unroll
    for (int e = 0; e < NEXP; ++e) if (e != i1 && p[e] > p[i2]) i2 = e;
    float w1 = p[i1], w2 = p[i2];
    float rs = 1.f / (w1 + w2);
    topi[2 * t] = i1;
    topi[2 * t + 1] = i2;
    topw[2 * t] = w1 * rs;
    topw[2 * t + 1] = w2 * rs;
  }
}

// ---------------- kernel 2: compaction (LDS-staged ballots) ----------------
__global__ __launch_bounds__(512) void compact_k(
    const int* __restrict__ topi, const float* __restrict__ topw,
    int* __restrict__ offsets, int* __restrict__ perm,
    float* __restrict__ wrow, int* __restrict__ inv) {
  int tid = threadIdx.x;
  int e = tid >> 6, lane = tid & 63;
  __shared__ unsigned char st[2 * T_TOK];
  __shared__ int scnt[NEXP];
  __shared__ int soff[NEXP + 1];
  for (int i = tid; i < (2 * T_TOK) / 4; i += 512) {
    int4 v = ((const int4*)topi)[i];
    uchar4 u;
    u.x = (unsigned char)v.x; u.y = (unsigned char)v.y;
    u.z = (unsigned char)v.z; u.w = (unsigned char)v.w;
    ((uchar4*)st)[i] = u;
  }
  __syncthreads();
  int c = 0;
  for (int j = lane; j < 2 * T_TOK; j += 64) {
    unsigned long long m = __ballot(st[j] == e);
    c += __popcll(m);
  }
  if (lane == 0) scnt[e] = c;
  __syncthreads();
  if (tid == 0) {
    int s = 0;
    for (int k = 0; k < NEXP; ++k) { soff[k] = s; s += scnt[k]; }
    soff[NEXP] = s;
    for (int k = 0; k <= NEXP; ++k) offsets[k] = soff[k];
  }
  __syncthreads();
  int base = soff[e];
  for (int j = lane; j < 2 * T_TOK; j += 64) {
    bool f = (st[j] == e);
    unsigned long long m = __ballot(f);
    if (f) {
      int p = base + __popcll(m & ((1ULL << lane) - 1ULL));
      perm[p] = j >> 1;
      wrow[p] = topw[j];
      inv[j] = p;
    }
    base += __popcll(m);
  }
}

// ---------------- fused weight convert+transpose (bank-optimal) ----------------
// One launch for all 3 weight tensors. 64x64 fp32 tile -> bf16 transposed.
// LDS layout: tl[c][64 r-elems], 8 slots of 16B per row, slot rotated by
// slot' = (r_slot + c) & 7.
// Phase 1: thread owns 2 cols x 8 rows (8x float2 global, 256B/row/wave),
//   packs 8 bf16 per col -> ONE 16B ds_write at rotated slot.
//   Per write inst: 8 lanes per bank-quad, all 32 banks = b128 structural min.
// Phase 2: ds_read_b128 at slot'=(cc+rr)&7 -> same uniform spread;
//   global stores 16B, 128B-contiguous per dst row.
__global__ __launch_bounds__(256) void tpose3_k(
    const float* __restrict__ weg, const float* __restrict__ wei,
    const float* __restrict__ weo, unsigned short* __restrict__ wgt,
    unsigned short* __restrict__ wit, unsigned short* __restrict__ wot) {
  int mat = blockIdx.z;
  int e = blockIdx.y;
  const float* src;
  unsigned short* dst;
  int SK, SN;
  if (mat == 0) { src = weg; dst = wgt; SK = DMODEL; SN = DMLP; }
  else if (mat == 1) { src = wei; dst = wit; SK = DMODEL; SN = DMLP; }
  else { src = weo; dst = wot; SK = DMLP; SN = DMODEL; }
  src += (size_t)e * DMODEL * DMLP;
  dst += (size_t)e * DMODEL * DMLP;
  int ntx = SN >> 6;
  int tile = blockIdx.x;
  int c0 = (tile & (ntx - 1)) * 64, k0 = (tile / ntx) * 64;

  __shared__ unsigned short tl[64 * 64];
  int tid = threadIdx.x;
  int j = tid & 31, g = tid >> 5;  // c-pair index, r-group (8 rows)
  int r0 = g * 8;

  const float* sp = src + (size_t)(k0 + r0) * SN + c0 + 2 * j;
  float2 v[8];
#pragma unroll
  for (int ri = 0; ri < 8; ++ri) v[ri] = *(const float2*)(sp + (size_t)ri * SN);
#pragma unroll
  for (int i = 0; i < 2; ++i) {
    int cc = 2 * j + i;
    u16x8 p;
#pragma unroll
    for (int ri = 0; ri < 8; ++ri)
      p[ri] = f2bf(i ? v[ri].y : v[ri].x);
    int sl = (g + cc) & 7;
    *(u16x8*)(&tl[cc * 64 + sl * 8]) = p;
  }
  __syncthreads();
#pragma unroll
  for (int i = 0; i < 2; ++i) {
    int task = tid + i * 256;
    int rr = task >> 3, cc = task & 7;  // dst row (=src col), k-slot
    int sl = (cc + rr) & 7;
    uint4 w = *(const uint4*)(&tl[rr * 64 + sl * 8]);
    *(uint4*)(dst + (size_t)(c0 + rr) * SK + k0 + cc * 8) = w;
  }
}

// ---------------- fused gate/in GEMM (m97 structure + slot rotation) ----------
// LDS rows pitch 32 elems (64B). 4 slots of 16B per row; content chunk s is
// stored at slot' = (s + (row>>1)) & 3 (via pre-swizzled gload16 source);
// fragment read for chunk q reads slot (q + (row>>1)) & 3.
// B tile rows: [0:32)=gate nb+0..31, [32:64)=in nb+0..31,
//              [64:96)=gate nb+32..63, [96:128)=in nb+32..63
__global__ __launch_bounds__(256) void hid2_k(
    const unsigned short* __restrict__ xb, const unsigned short* __restrict__ wgt,
    const unsigned short* __restrict__ wit, const int* __restrict__ offsets,
    const int* __restrict__ perm, const float* __restrict__ wrow,
    unsigned short* __restrict__ hid) {
  int e = blockIdx.z;
  int off = offsets[e], end = offsets[e + 1];
  int cnt = end - off;
  int m0 = blockIdx.y * 128;
  if (m0 >= cnt) return;
  int nb = blockIdx.x * 64;

  __shared__ unsigned short As[128 * 32];
  __shared__ unsigned short Bs[128 * 32];

  int tid = threadIdx.x;
  int lane = tid & 63, wid = tid >> 6;
  int wm = (wid & 1) * 64, wn = (wid >> 1) * 64;
  int lr = lane & 15, q = lane >> 4;

  f32x4 acc[4][4];
  f32x4 z = {0.f, 0.f, 0.f, 0.f};
#pragma unroll
  for (int i = 0; i < 4; ++i)
#pragma unroll
    for (int j = 0; j < 4; ++j) acc[i][j] = z;

  const unsigned short* aptr[2];
  const unsigned short* bptr[2];
#pragma unroll
  for (int it = 0; it < 2; ++it) {
    int task = tid + it * 256;
    int r = task >> 2, sp4 = task & 3;
    int ch = (sp4 - (r >> 1)) & 3;  // inverse rotation on global source
    int pl = m0 + r;
    int src = perm[off + ((pl < cnt) ? pl : 0)];
    aptr[it] = xb + (size_t)src * DMODEL + ch * 8;
    int arr = (r >> 5) & 1;
    int col = nb + (r & 31) + ((r >> 6) << 5);
    const unsigned short* w = (arr ? wit : wgt) + (size_t)e * DMLP * DMODEL;
    bptr[it] = w + (size_t)col * DMODEL + ch * 8;
  }

  for (int k0 = 0; k0 < DMODEL; k0 += 32) {
#pragma unroll
    for (int it = 0; it < 2; ++it) {
      gload16(aptr[it] + k0, &As[(tid + it * 256) * 8]);
      gload16(bptr[it] + k0, &Bs[(tid + it * 256) * 8]);
    }
    __syncthreads();
    bf16x8 af[4], bfr[4];
#pragma unroll
    for (int i = 0; i < 4; ++i) {
      int R = wm + i * 16 + lr;
      af[i] = *(const bf16x8*)(&As[R * 32 + (((q + (R >> 1)) & 3) * 8)]);
    }
#pragma unroll
    for (int j = 0; j < 4; ++j) {
      int R = wn + j * 16 + lr;
      bfr[j] = *(const bf16x8*)(&Bs[R * 32 + (((q + (R >> 1)) & 3) * 8)]);
    }
#pragma unroll
    for (int i = 0; i < 4; ++i)
#pragma unroll
      for (int j = 0; j < 4; ++j)
        acc[i][j] = __builtin_amdgcn_mfma_f32_16x16x32_bf16(af[i], bfr[j],
                                                            acc[i][j], 0, 0, 0);
    __syncthreads();
  }

  int colbase = nb + (wn ? 32 : 0);
#pragma unroll
  for (int i = 0; i < 4; ++i) {
#pragma unroll
    for (int jp = 0; jp < 2; ++jp) {
#pragma unroll
      for (int r = 0; r < 4; ++r) {
        int row = wm + i * 16 + q * 4 + r;
        int pl = m0 + row;
        if (pl < cnt) {
          int pos = off + pl;
          float g = acc[i][jp][r], vv = acc[i][jp + 2][r];
          float hv = (g / (1.f + expf(-g))) * vv * wrow[pos];
          hid[(size_t)pos * DMLP + colbase + jp * 16 + lr] = f2bf(hv);
        }
      }
    }
  }
}

// ---------------- out GEMM: 128m x 64n tile (2x occupancy) + rotation --------
__global__ __launch_bounds__(256) void out2_k(
    const unsigned short* __restrict__ hid, const unsigned short* __restrict__ wot,
    const int* __restrict__ offsets, float* __restrict__ tmp) {
  int e = blockIdx.z;
  int off = offsets[e], end = offsets[e + 1];
  int cnt = end - off;
  int m0 = blockIdx.y * 128;
  if (m0 >= cnt) return;
  int n0 = blockIdx.x * 64;

  __shared__ unsigned short As[128 * 32];
  __shared__ unsigned short Bs[64 * 32];

  int tid = threadIdx.x;
  int lane = tid & 63, wid = tid >> 6;
  int wm = (wid & 1) * 64, wn = (wid >> 1) * 32;
  int lr = lane & 15, q = lane >> 4;

  f32x4 acc[4][2];
  f32x4 z = {0.f, 0.f, 0.f, 0.f};
#pragma unroll
  for (int i = 0; i < 4; ++i)
#pragma unroll
    for (int j = 0; j < 2; ++j) acc[i][j] = z;

  const unsigned short* aptr[2];
  const unsigned short* bptr;
#pragma unroll
  for (int it = 0; it < 2; ++it) {
    int task = tid + it * 256;
    int r = task >> 2, sp4 = task & 3;
    int ch = (sp4 - (r >> 1)) & 3;
    int pl = m0 + r;
    aptr[it] = hid + (size_t)(off + ((pl < cnt) ? pl : 0)) * DMLP + ch * 8;
  }
  {
    int r = tid >> 2, sp4 = tid & 3;
    int ch = (sp4 - (r >> 1)) & 3;
    bptr = wot + (size_t)e * DMODEL * DMLP + (size_t)(n0 + r) * DMLP + ch * 8;
  }

  for (int k0 = 0; k0 < DMLP; k0 += 32) {
#pragma unroll
    for (int it = 0; it < 2; ++it)
      gload16(aptr[it] + k0, &As[(tid + it * 256) * 8]);
    gload16(bptr + k0, &Bs[tid * 8]);
    __syncthreads();
    bf16x8 af[4], bfr[2];
#pragma unroll
    for (int i = 0; i < 4; ++i) {
      int R = wm + i * 16 + lr;
      af[i] = *(const bf16x8*)(&As[R * 32 + (((q + (R >> 1)) & 3) * 8)]);
    }
#pragma unroll
    for (int j = 0; j < 2; ++j) {
      int R = wn + j * 16 + lr;
      bfr[j] = *(const bf16x8*)(&Bs[R * 32 + (((q + (R >> 1)) & 3) * 8)]);
    }
#pragma unroll
    for (int i = 0; i < 4; ++i)
#pragma unroll
      for (int j = 0; j < 2; ++j)
        acc[i][j] = __builtin_amdgcn_mfma_f32_16x16x32_bf16(af[i], bfr[j],
                                                            acc[i][j], 0, 0, 0);
    __syncthreads();
  }

#pragma unroll
  for (int i = 0; i < 4; ++i)
#pragma unroll
    for (int j = 0; j < 2; ++j)
#pragma unroll
      for (int r = 0; r < 4; ++r) {
        int row = wm + i * 16 + q * 4 + r;
        int pl = m0 + row;
        if (pl < cnt) {
          tmp[(size_t)(off + pl) * DMODEL + n0 + wn + j * 16 + lr] =
              acc[i][j][r];
        }
      }
}

// combine: out[t] = tmp[inv[2t]] + tmp[inv[2t+1]]
__global__ __launch_bounds__(256) void comb_k(const float* __restrict__ tmp,
                                              const int* __restrict__ inv,
                                              float* __restrict__ out) {
  int t = blockIdx.x, c = threadIdx.x;
  int i0 = inv[2 * t], i1 = inv[2 * t + 1];
  const float4* t4 = (const float4*)tmp;
  float4 a = t4[(size_t)i0 * 256 + c];
  float4 b = t4[(size_t)i1 * 256 + c];
  float4 o;
  o.x = a.x + b.x; o.y = a.y + b.y; o.z = a.z + b.z; o.w = a.w + b.w;
  ((float4*)out)[(size_t)t * 256 + c] = o;
}

// =====================================================================
// FALLBACK PATH (verified, used when ws_size < 245 MiB)
// =====================================================================
#define BPITCH 40

__global__ __launch_bounds__(256) void hid_k(
    const float* __restrict__ x, const float* __restrict__ weg,
    const float* __restrict__ wei, const int* __restrict__ offsets,
    const int* __restrict__ perm, const float* __restrict__ wrow,
    unsigned short* __restrict__ hid) {
  int e = blockIdx.z;
  int off = offsets[e], end = offsets[e + 1];
  int cnt = end - off;
  int m0 = blockIdx.y * 128;
  if (m0 >= cnt) return;
  int nb = blockIdx.x * 64;
  const float* wg = weg + (size_t)e * DMODEL * DMLP;
  const float* wi = wei + (size_t)e * DMODEL * DMLP;

  __shared__ unsigned short As[128 * BPITCH];
  __shared__ unsigned short Bg[64 * BPITCH];
  __shared__ unsigned short Bi[64 * BPITCH];

  int tid = threadIdx.x;
  int lane = tid & 63, wid = tid >> 6;
  int wm = (wid & 1) * 64, wn = (wid >> 1) * 32;
  int lr = lane & 15, q = lane >> 4;

  f32x4 accg[4][2], acci[4][2];
  f32x4 z = {0.f, 0.f, 0.f, 0.f};
#pragma unroll
  for (int i = 0; i < 4; ++i)
#pragma unroll
    for (int j = 0; j < 2; ++j) { accg[i][j] = z; acci[i][j] = z; }

  const float* aptr[4];
  int adst[4];
#pragma unroll
  for (int it = 0; it < 4; ++it) {
    int task = tid + it * 256;
    int r = task >> 3, kc = (task & 7) * 4;
    int pl = m0 + r;
    int src = perm[off + ((pl < cnt) ? pl : 0)];
    aptr[it] = x + (size_t)src * DMODEL + kc;
    adst[it] = r * BPITCH + kc;
  }
  int tn = (tid & 15) * 4, tk = (tid >> 4) * 2;

  for (int k0 = 0; k0 < DMODEL; k0 += 32) {
#pragma unroll
    for (int it = 0; it < 4; ++it) {
      float4 v = *(const float4*)(aptr[it] + k0);
      ushort4 u;
      u.x = f2bf(v.x); u.y = f2bf(v.y); u.z = f2bf(v.z); u.w = f2bf(v.w);
      *(ushort4*)(&As[adst[it]]) = u;
    }
    {
      const float* pg = wg + (size_t)(k0 + tk) * DMLP + nb + tn;
      float4 g0 = *(const float4*)(pg);
      float4 g1 = *(const float4*)(pg + DMLP);
      const float* pi = wi + (size_t)(k0 + tk) * DMLP + nb + tn;
      float4 i0 = *(const float4*)(pi);
      float4 i1 = *(const float4*)(pi + DMLP);
      const float* c0 = (const float*)&g0;
      const float* c1 = (const float*)&g1;
      const float* d0 = (const float*)&i0;
      const float* d1 = (const float*)&i1;
#pragma unroll
      for (int cix = 0; cix < 4; ++cix) {
        ushort2 vg; vg.x = f2bf(c0[cix]); vg.y = f2bf(c1[cix]);
        *(ushort2*)(&Bg[(tn + cix) * BPITCH + tk]) = vg;
        ushort2 vi; vi.x = f2bf(d0[cix]); vi.y = f2bf(d1[cix]);
        *(ushort2*)(&Bi[(tn + cix) * BPITCH + tk]) = vi;
      }
    }
    __syncthreads();
    bf16x8 af[4], bgf[2], bif[2];
#pragma unroll
    for (int i = 0; i < 4; ++i)
      af[i] = *(const bf16x8*)(&As[(wm + i * 16 + lr) * BPITCH + q * 8]);
#pragma unroll
    for (int j = 0; j < 2; ++j) {
      bgf[j] = *(const bf16x8*)(&Bg[(wn + j * 16 + lr) * BPITCH + q * 8]);
      bif[j] = *(const bf16x8*)(&Bi[(wn + j * 16 + lr) * BPITCH + q * 8]);
    }
#pragma unroll
    for (int i = 0; i < 4; ++i)
#pragma unroll
      for (int j = 0; j < 2; ++j) {
        accg[i][j] = __builtin_amdgcn_mfma_f32_16x16x32_bf16(af[i], bgf[j], accg[i][j], 0, 0, 0);
        acci[i][j] = __builtin_amdgcn_mfma_f32_16x16x32_bf16(af[i], bif[j], acci[i][j], 0, 0, 0);
      }
    __syncthreads();
  }
#pragma unroll
  for (int i = 0; i < 4; ++i)
#pragma unroll
    for (int j = 0; j < 2; ++j)
#pragma unroll
      for (int r = 0; r < 4; ++r) {
        int row = wm + i * 16 + q * 4 + r;
        int pl = m0 + row;
        if (pl < cnt) {
          int pos = off + pl;
          float g = accg[i][j][r], vv = acci[i][j][r];
          float hv = (g / (1.f + expf(-g))) * vv * wrow[pos];
          hid[(size_t)pos * DMLP + nb + wn + j * 16 + lr] = f2bf(hv);
        }
      }
}

__global__ __launch_bounds__(256) void out_k(
    const unsigned short* __restrict__ hid, const float* __restrict__ weo,
    const int* __restrict__ offsets, const int* __restrict__ perm,
    float* __restrict__ out) {
  int e = blockIdx.z;
  int off = offsets[e], end = offsets[e + 1];
  int cnt = end - off;
  int m0 = blockIdx.y * 128;
  if (m0 >= cnt) return;
  int nb = blockIdx.x * 64;
  const float* wo = weo + (size_t)e * DMLP * DMODEL;

  __shared__ unsigned short As[128 * BPITCH];
  __shared__ unsigned short Bs[64 * BPITCH];

  int tid = threadIdx.x;
  int lane = tid & 63, wid = tid >> 6;
  int wm = (wid & 1) * 64, wn = (wid >> 1) * 32;
  int lr = lane & 15, q = lane >> 4;

  f32x4 acc[4][2];
  f32x4 z = {0.f, 0.f, 0.f, 0.f};
#pragma unroll
  for (int i = 0; i < 4; ++i)
#pragma unroll
    for (int j = 0; j < 2; ++j) acc[i][j] = z;

  const unsigned short* aptr[2];
  int adst[2];
#pragma unroll
  for (int it = 0; it < 2; ++it) {
    int task = tid + it * 256;
    int r = task >> 2, kg = (task & 3) * 8;
    int pl = m0 + r;
    int src = off + ((pl < cnt) ? pl : 0);
    aptr[it] = hid + (size_t)src * DMLP + kg;
    adst[it] = r * BPITCH + kg;
  }
  int tn = (tid & 15) * 4, tk = (tid >> 4) * 2;

  for (int k0 = 0; k0 < DMLP; k0 += 32) {
#pragma unroll
    for (int it = 0; it < 2; ++it) {
      uint4 v = *(const uint4*)(aptr[it] + k0);
      *(uint4*)(&As[adst[it]]) = v;
    }
    {
      const float* pb = wo + (size_t)(k0 + tk) * DMODEL + nb + tn;
      float4 b0 = *(const float4*)(pb);
      float4 b1 = *(const float4*)(pb + DMODEL);
      const float* c0 = (const float*)&b0;
      const float* c1 = (const float*)&b1;
#pragma unroll
      for (int cix = 0; cix < 4; ++cix) {
        ushort2 vb; vb.x = f2bf(c0[cix]); vb.y = f2bf(c1[cix]);
        *(ushort2*)(&Bs[(tn + cix) * BPITCH + tk]) = vb;
      }
    }
    __syncthreads();
    bf16x8 af[4], bf[2];
#pragma unroll
    for (int i = 0; i < 4; ++i)
      af[i] = *(const bf16x8*)(&As[(wm + i * 16 + lr) * BPITCH + q * 8]);
#pragma unroll
    for (int j = 0; j < 2; ++j)
      bf[j] = *(const bf16x8*)(&Bs[(wn + j * 16 + lr) * BPITCH + q * 8]);
#pragma unroll
    for (int i = 0; i < 4; ++i)
#pragma unroll
      for (int j = 0; j < 2; ++j)
        acc[i][j] = __builtin_amdgcn_mfma_f32_16x16x32_bf16(af[i], bf[j], acc[i][j], 0, 0, 0);
    __syncthreads();
  }
#pragma unroll
  for (int i = 0; i < 4; ++i)
#pragma unroll
    for (int j = 0; j < 2; ++j)
#pragma unroll
      for (int r = 0; r < 4; ++r) {
        int row = wm + i * 16 + q * 4 + r;
        int pl = m0 + row;
        if (pl < cnt) {
          int tok = perm[off + pl];
          atomicAdd(&out[(size_t)tok * DMODEL + nb + wn + j * 16 + lr],
                    acc[i][j][r]);
        }
      }
}

// ---------------- launcher ----------------
extern "C" void kernel_launch(void* const* d_in, const int* in_sizes, int n_in,
                              void* d_out, int out_size, void* d_ws,
                              size_t ws_size, hipStream_t stream) {
  const float* x = (const float*)d_in[0];
  const float* wgate = (const float*)d_in[1];
  const float* weg = (const float*)d_in[2];
  const float* wei = (const float*)d_in[3];
  const float* weo = (const float*)d_in[4];
  float* out = (float*)d_out;

  char* ws = (char*)d_ws;
  const size_t KB = 1024, MB = 1048576;
  int* topi = (int*)(ws + 0 * KB);        // 16 KB
  float* topw = (float*)(ws + 16 * KB);   // 16 KB
  int* offsets = (int*)(ws + 32 * KB);    // 1 KB
  int* perm = (int*)(ws + 33 * KB);       // 16 KB
  float* wrow = (float*)(ws + 49 * KB);   // 16 KB
  int* inv = (int*)(ws + 65 * KB);        // 16 KB

  bool big = ws_size >= (size_t)245 * MB;
  unsigned short* xb = big ? (unsigned short*)(ws + 1 * MB) : nullptr;

  router_k<<<dim3(T_TOK), dim3(64), 0, stream>>>(x, wgate, topi, topw, xb);
  compact_k<<<dim3(1), dim3(512), 0, stream>>>(topi, topw, offsets, perm, wrow, inv);

  if (big) {
    // xb 4MiB@1MB, hid 32MiB@5MB, tmp 16MiB@37MB, wgt/wit/wot 64MiB @53/117/181MB
    unsigned short* hid = (unsigned short*)(ws + 5 * MB);
    float* tmp = (float*)(ws + 37 * MB);
    unsigned short* wgt = (unsigned short*)(ws + 53 * MB);
    unsigned short* wit = (unsigned short*)(ws + 117 * MB);
    unsigned short* wot = (unsigned short*)(ws + 181 * MB);

    // 1024 64x64-tiles per (expert, matrix); z: 0=gate 1=in 2=out
    tpose3_k<<<dim3(1024, NEXP, 3), dim3(256), 0, stream>>>(weg, wei, weo,
                                                            wgt, wit, wot);
    hid2_k<<<dim3(DMLP / 64, T_TOK / 128, NEXP), dim3(256), 0, stream>>>(
        xb, wgt, wit, offsets, perm, wrow, hid);
    out2_k<<<dim3(DMODEL / 64, T_TOK / 128, NEXP), dim3(256), 0, stream>>>(
        hid, wot, offsets, tmp);
    comb_k<<<dim3(T_TOK), dim3(256), 0, stream>>>(tmp, inv, out);
  } else {
    unsigned short* hid = (unsigned short*)(ws + 96 * KB);
    hipMemsetAsync(d_out, 0, (size_t)out_size * sizeof(float), stream);
    hid_k<<<dim3(DMLP / 64, T_TOK / 128, NEXP), dim3(256), 0, stream>>>(
        x, weg, wei, offsets, perm, wrow, hid);
    out_k<<<dim3(DMODEL / 64, T_TOK / 128, NEXP), dim3(256), 0, stream>>>(
        hid, weo, offsets, perm, out);
  }
}